// Round 2
// baseline (831.984 us; speedup 1.0000x reference)
//
#include <hip/hip_runtime.h>

#define D_MODEL 2048
#define N_HEADS 32
#define D_HEAD  64
#define CHUNK   128
#define SEQ     2048
#define BZ      4
#define NC      16            // SEQ/CHUNK
#define NTOK    (BZ*SEQ)      // 8192
#define LN_EPS  1e-5f

typedef __bf16 bf16_t;
typedef bf16_t bf16x8 __attribute__((ext_vector_type(8)));
typedef float  f32x4  __attribute__((ext_vector_type(4)));

#define GLOBAL_AS __attribute__((address_space(1)))
#define LDS_AS    __attribute__((address_space(3)))

// ---------------------------------------------------------------------------
// K1: LayerNorm + token-shift time-mix -> rx,kx,vx (bf16). Also writes
// xn[:, -1, :] (output 1). One block per token; LN of the previous token is
// recomputed (cheap, L2-hot) instead of materializing xn.
// ---------------------------------------------------------------------------
__global__ __launch_bounds__(256) void k_ln_mix(
    const float* __restrict__ x, const float* __restrict__ tmr,
    const float* __restrict__ tmk, const float* __restrict__ tmv,
    const float* __restrict__ g1, const float* __restrict__ b1,
    bf16_t* __restrict__ rxb, bf16_t* __restrict__ kxb, bf16_t* __restrict__ vxb,
    float* __restrict__ xn_last)
{
    __shared__ float sbuf[16];
    const int row = blockIdx.x;
    const int t = row & (SEQ-1);
    const int tid = threadIdx.x;
    const float4* xc4 = (const float4*)(x + (size_t)row*D_MODEL);
    float4 c0 = xc4[tid*2], c1 = xc4[tid*2+1];
    float4 p0 = {0,0,0,0}, p1 = {0,0,0,0};
    const bool hasprev = (t != 0);
    if (hasprev){
        const float4* xp4 = (const float4*)(x + (size_t)(row-1)*D_MODEL);
        p0 = xp4[tid*2]; p1 = xp4[tid*2+1];
    }
    float xc[8] = {c0.x,c0.y,c0.z,c0.w,c1.x,c1.y,c1.z,c1.w};
    float xp[8] = {p0.x,p0.y,p0.z,p0.w,p1.x,p1.y,p1.z,p1.w};
    float sc=0.f, qc=0.f, sp=0.f, qp=0.f;
    for (int q=0;q<8;++q){ sc+=xc[q]; qc+=xc[q]*xc[q]; sp+=xp[q]; qp+=xp[q]*xp[q]; }
    for (int o=1;o<64;o<<=1){
        sc += __shfl_xor(sc,o,64); qc += __shfl_xor(qc,o,64);
        sp += __shfl_xor(sp,o,64); qp += __shfl_xor(qp,o,64);
    }
    const int wave = tid>>6, lane = tid&63;
    if (lane==0){ sbuf[wave*4+0]=sc; sbuf[wave*4+1]=qc; sbuf[wave*4+2]=sp; sbuf[wave*4+3]=qp; }
    __syncthreads();
    sc = sbuf[0]+sbuf[4]+sbuf[8]+sbuf[12];
    qc = sbuf[1]+sbuf[5]+sbuf[9]+sbuf[13];
    sp = sbuf[2]+sbuf[6]+sbuf[10]+sbuf[14];
    qp = sbuf[3]+sbuf[7]+sbuf[11]+sbuf[15];
    const float inv = 1.f/(float)D_MODEL;
    float muc = sc*inv, varc = qc*inv - muc*muc;
    float rc  = rsqrtf(varc + LN_EPS);
    float mup = sp*inv, varp = qp*inv - mup*mup;
    float rp  = rsqrtf(varp + LN_EPS);
    bf16x8 rv, kv, vv;
    const int ci = tid*8;
    float xnl[8];
    for (int q=0;q<8;++q){
        int c = ci+q;
        float gg = g1[c], bb = b1[c];
        float xn = (xc[q]-muc)*rc*gg + bb;
        float sh = hasprev ? ((xp[q]-mup)*rp*gg + bb) : 0.f;  // shift row 0 is literal 0
        float mr = tmr[c], mk = tmk[c], mv = tmv[c];
        rv[q] = (bf16_t)(xn*mr + (1.f-mr)*sh);
        kv[q] = (bf16_t)(xn*mk + (1.f-mk)*sh);
        vv[q] = (bf16_t)(xn*mv + (1.f-mv)*sh);
        xnl[q] = xn;
    }
    size_t base = (size_t)row*D_MODEL + ci;
    *(bf16x8*)&rxb[base] = rv;
    *(bf16x8*)&kxb[base] = kv;
    *(bf16x8*)&vxb[base] = vv;
    if (t == SEQ-1){
        int b = row >> 11;
        for (int q=0;q<8;++q) xn_last[(size_t)b*D_MODEL + ci + q] = xnl[q];
    }
}

// ---------------------------------------------------------------------------
// K2: transpose + f32->bf16 convert one weight matrix: WT[n][k] = W[k][n].
// ---------------------------------------------------------------------------
__global__ __launch_bounds__(256) void k_wt(const float* __restrict__ W, bf16_t* __restrict__ WT)
{
    __shared__ float tile[64][65];
    const int n0 = blockIdx.x*64, k0 = blockIdx.y*64;
    const int j = threadIdx.x & 63, i0 = threadIdx.x >> 6;
    for (int it=0; it<16; ++it){
        int i = i0 + it*4;
        tile[j][i] = W[(size_t)(k0+i)*D_MODEL + n0 + j];
    }
    __syncthreads();
    for (int it=0; it<16; ++it){
        int idx = threadIdx.x + it*256;
        int r = idx >> 6, c = idx & 63;
        WT[(size_t)(n0+r)*D_MODEL + k0 + c] = (bf16_t)tile[r][c];
    }
}

// ---------------------------------------------------------------------------
// K3: bf16 GEMM, C = A(MxK) * B^T(NxK)^T. m97 structure: 128x128 tile,
// BK=32, global_load_lds width=16 staging into UNPADDED LDS (layout must be
// contiguous in lane order: segment s -> LDS offset s*16B), ds_read_b128
// fragments, 4 waves of 64x64, mfma_f32_16x16x32_bf16.
// OUT_BF16=1: store bf16. OUT_BF16=0: f32 out with fused residual add.
// ---------------------------------------------------------------------------
template<int OUT_BF16>
__global__ __launch_bounds__(256) void k_gemm_bt(
    const bf16_t* __restrict__ A, const bf16_t* __restrict__ B,
    void* __restrict__ Cout, const float* __restrict__ resid, int N, int K)
{
    __shared__ __align__(16) bf16_t As[128*32];
    __shared__ __align__(16) bf16_t Bs[128*32];
    const int tid = threadIdx.x;
    const int wave = tid>>6, lane = tid&63;
    const int quad = lane>>4, l15 = lane&15;
    const int wm = (wave>>1)*64, wn = (wave&1)*64;
    const size_t arow0 = (size_t)blockIdx.y*128;
    const size_t brow0 = (size_t)blockIdx.x*128;
    // staging decomposition: segment s in [0,512): row = s>>2, colseg = s&3.
    // s = tid + it*256; wave w covers 64 consecutive segments -> LDS dest
    // (wave-uniform base + lane*16) matches &As[s*8] exactly.
    const int r0a = tid>>2, ca = (tid&3)*8;
    f32x4 acc[4][4];
    for (int i=0;i<4;++i) for (int j=0;j<4;++j) acc[i][j] = (f32x4){0.f,0.f,0.f,0.f};
    for (int k0=0; k0<K; k0+=32){
        #pragma unroll
        for (int it=0; it<2; ++it){
            int s   = tid + it*256;
            int row = r0a + it*64;
            __builtin_amdgcn_global_load_lds(
                (const GLOBAL_AS void*)&A[(arow0+row)*K + k0 + ca],
                (LDS_AS void*)&As[s*8], 16, 0, 0);
            __builtin_amdgcn_global_load_lds(
                (const GLOBAL_AS void*)&B[(brow0+row)*K + k0 + ca],
                (LDS_AS void*)&Bs[s*8], 16, 0, 0);
        }
        __syncthreads();
        bf16x8 af[4], bfr[4];
        for (int i=0;i<4;++i){
            af[i]  = *(const bf16x8*)&As[(wm+i*16+l15)*32 + quad*8];
            bfr[i] = *(const bf16x8*)&Bs[(wn+i*16+l15)*32 + quad*8];
        }
        for (int i=0;i<4;++i)
            for (int j=0;j<4;++j)
                acc[i][j] = __builtin_amdgcn_mfma_f32_16x16x32_bf16(af[i], bfr[j], acc[i][j], 0,0,0);
        __syncthreads();
    }
    for (int i=0;i<4;++i) for (int j=0;j<4;++j){
        for (int e=0;e<4;++e){
            size_t r = arow0 + wm + i*16 + quad*4 + e;
            size_t c = brow0 + wn + j*16 + l15;
            float v = acc[i][j][e];
            if (OUT_BF16) ((bf16_t*)Cout)[r*(size_t)N + c] = (bf16_t)v;
            else          ((float*) Cout)[r*(size_t)N + c] = resid[r*(size_t)N + c] + v;
        }
    }
}

// ---------------------------------------------------------------------------
// K4a: per (b,chunk,h): S = (r k^T) * w_mask (bf16 round-trip through LDS),
// sep = S v (f32 out). LDS overlay: SS reuses rS+kS after a barrier -> 53 KB.
// ---------------------------------------------------------------------------
__global__ __launch_bounds__(256) void k_chunk_att(
    const bf16_t* __restrict__ rb, const bf16_t* __restrict__ kb, const bf16_t* __restrict__ vb,
    const float* __restrict__ td, const float* __restrict__ tf, float* __restrict__ sep)
{
    __shared__ __align__(16) char smem[54272];
    bf16_t* rS = (bf16_t*)smem;               // [128][72]
    bf16_t* kS = (bf16_t*)(smem + 18432);     // [128][72]
    bf16_t* SS = (bf16_t*)smem;               // [128][136] overlays rS+kS
    bf16_t* vT = (bf16_t*)(smem + 36864);     // [64][136], vT[d][j] = v[j][d]
    const int bid = blockIdx.x;
    const int h = bid & 31, n = (bid>>5)&15, b = bid>>9;
    const int tid = threadIdx.x;
    const int wave = tid>>6, lane = tid&63, quad = lane>>4, l15 = lane&15;
    const size_t row0 = (size_t)b*SEQ + n*CHUNK;
    const int col0 = h*D_HEAD;
    const float lnw = -__expf(td[h]);
    const float u   =  __expf(tf[h]);
    for (int it=0; it<4; ++it){
        int idx = tid + it*256;
        int row = idx>>3, c8 = (idx&7)*8;
        *(bf16x8*)&rS[row*72 + c8] = *(const bf16x8*)&rb[(row0+row)*D_MODEL + col0 + c8];
        *(bf16x8*)&kS[row*72 + c8] = *(const bf16x8*)&kb[(row0+row)*D_MODEL + col0 + c8];
        bf16x8 vv = *(const bf16x8*)&vb[(row0+row)*D_MODEL + col0 + c8];
        for (int q=0;q<8;++q) vT[(c8+q)*136 + row] = vv[q];
    }
    __syncthreads();
    f32x4 accS[2][8];
    for (int i=0;i<2;++i) for (int j=0;j<8;++j) accS[i][j] = (f32x4){0.f,0.f,0.f,0.f};
    for (int kk=0; kk<2; ++kk){
        bf16x8 af[2], bfr[8];
        for (int i=0;i<2;++i) af[i] = *(const bf16x8*)&rS[(wave*32+i*16+l15)*72 + kk*32 + quad*8];
        for (int j=0;j<8;++j) bfr[j] = *(const bf16x8*)&kS[(j*16+l15)*72 + kk*32 + quad*8];
        for (int i=0;i<2;++i) for (int j=0;j<8;++j)
            accS[i][j] = __builtin_amdgcn_mfma_f32_16x16x32_bf16(af[i], bfr[j], accS[i][j], 0,0,0);
    }
    __syncthreads();   // everyone done reading rS/kS before SS overlays them
    for (int i=0;i<2;++i) for (int j=0;j<8;++j) for (int e=0;e<4;++e){
        int si = wave*32 + i*16 + quad*4 + e;
        int sj = j*16 + l15;
        float m;
        if (si > sj)      m = __expf(lnw * (float)(si-sj-1));
        else if (si == sj) m = u;
        else               m = 0.f;
        SS[si*136 + sj] = (bf16_t)(accS[i][j][e] * m);
    }
    __syncthreads();
    f32x4 accP[2][4];
    for (int i=0;i<2;++i) for (int j=0;j<4;++j) accP[i][j] = (f32x4){0.f,0.f,0.f,0.f};
    for (int kk=0; kk<4; ++kk){
        bf16x8 af[2], bfr[4];
        for (int i=0;i<2;++i) af[i] = *(const bf16x8*)&SS[(wave*32+i*16+l15)*136 + kk*32 + quad*8];
        for (int j=0;j<4;++j) bfr[j] = *(const bf16x8*)&vT[(j*16+l15)*136 + kk*32 + quad*8];
        for (int i=0;i<2;++i) for (int j=0;j<4;++j)
            accP[i][j] = __builtin_amdgcn_mfma_f32_16x16x32_bf16(af[i], bfr[j], accP[i][j], 0,0,0);
    }
    float* sepb = sep + (size_t)bid*(CHUNK*D_HEAD);
    for (int i=0;i<2;++i) for (int j=0;j<4;++j) for (int e=0;e<4;++e){
        int si = wave*32 + i*16 + quad*4 + e;
        int d  = j*16 + l15;
        sepb[si*D_HEAD + d] = accP[i][j][e];
    }
}

// ---------------------------------------------------------------------------
// K4b: per (b,chunk,h): U[e][d] = sum_j k[j][e] * w^(C-1-j) * v[j][d]
// ---------------------------------------------------------------------------
__global__ __launch_bounds__(256) void k_chunk_U(
    const bf16_t* __restrict__ kb, const bf16_t* __restrict__ vb,
    const float* __restrict__ td, float* __restrict__ U)
{
    __shared__ __align__(16) bf16_t kT[64*136];   // kT[e][j] = k[j][e]*w^(127-j)
    __shared__ __align__(16) bf16_t vT[64*136];   // vT[d][j] = v[j][d]
    const int bid = blockIdx.x;
    const int h = bid & 31, n = (bid>>5)&15, b = bid>>9;
    const int tid = threadIdx.x;
    const int wave = tid>>6, lane = tid&63, quad = lane>>4, l15 = lane&15;
    const size_t row0 = (size_t)b*SEQ + n*CHUNK;
    const int col0 = h*D_HEAD;
    const float lnw = -__expf(td[h]);
    for (int it=0; it<4; ++it){
        int idx = tid + it*256;
        int row = idx>>3, c8 = (idx&7)*8;
        float wj = __expf(lnw * (float)(CHUNK-1-row));
        bf16x8 kv = *(const bf16x8*)&kb[(row0+row)*D_MODEL + col0 + c8];
        bf16x8 vv = *(const bf16x8*)&vb[(row0+row)*D_MODEL + col0 + c8];
        for (int q=0;q<8;++q){
            kT[(c8+q)*136 + row] = (bf16_t)((float)kv[q] * wj);
            vT[(c8+q)*136 + row] = vv[q];
        }
    }
    __syncthreads();
    f32x4 accU[4];
    for (int j=0;j<4;++j) accU[j] = (f32x4){0.f,0.f,0.f,0.f};
    for (int kk=0; kk<4; ++kk){
        bf16x8 af = *(const bf16x8*)&kT[(wave*16+l15)*136 + kk*32 + quad*8];
        bf16x8 bfr[4];
        for (int j=0;j<4;++j) bfr[j] = *(const bf16x8*)&vT[(j*16+l15)*136 + kk*32 + quad*8];
        for (int j=0;j<4;++j)
            accU[j] = __builtin_amdgcn_mfma_f32_16x16x32_bf16(af, bfr[j], accU[j], 0,0,0);
    }
    float* Ub = U + (size_t)bid*(D_HEAD*D_HEAD);
    for (int j=0;j<4;++j) for (int e=0;e<4;++e){
        int ei = wave*16 + quad*4 + e;
        int d  = j*16 + l15;
        Ub[ei*D_HEAD + d] = accU[j][e];
    }
}

// ---------------------------------------------------------------------------
// K5: sequential prefix over chunks (per b,h): emit per-chunk incoming state
// (bf16, transposed [d][e] for the bias MFMA B-operand) and final state (out 2).
// ---------------------------------------------------------------------------
__global__ __launch_bounds__(256) void k_scan(
    const float* __restrict__ U, const float* __restrict__ td,
    bf16_t* __restrict__ stT, float* __restrict__ outState)
{
    const int bh = blockIdx.x;
    const int h = bh & 31, b = bh >> 5;
    const int tid = threadIdx.x;
    const float lnw = -__expf(td[h]);
    const float wC  =  __expf(lnw * (float)CHUNK);
    float st[16];
    for (int q=0;q<16;++q) st[q] = 0.f;
    for (int n=0;n<NC;++n){
        size_t base = ((size_t)((b*NC + n)*N_HEADS + h))*4096;
        for (int q=0;q<16;++q){
            int f = tid + q*256;
            int e = f>>6, d = f&63;
            stT[base + d*64 + e] = (bf16_t)st[q];       // incoming state for chunk n
            st[q] = st[q]*wC + U[base + f];
        }
    }
    size_t ob = ((size_t)(b*N_HEADS + h))*4096;
    for (int q=0;q<16;++q) outState[ob + tid + q*256] = st[q];
}

// ---------------------------------------------------------------------------
// K6: per (b,chunk,h): bias = (r @ state)*w^i, att_pre = sep + bias,
// LayerNorm over d_head with lnx scale/bias, write att (bf16, token-major).
// ---------------------------------------------------------------------------
__global__ __launch_bounds__(256) void k_bias_ln(
    const bf16_t* __restrict__ rb, const bf16_t* __restrict__ stT,
    const float* __restrict__ sep, const float* __restrict__ td,
    const float* __restrict__ gx, const float* __restrict__ bx,
    bf16_t* __restrict__ att)
{
    __shared__ __align__(16) bf16_t rS[128*72];
    __shared__ __align__(16) bf16_t sS[64*72];
    __shared__ float ap[128*68];
    __shared__ float mu_s[128], rs_s[128];
    const int bid = blockIdx.x;
    const int h = bid & 31, n = (bid>>5)&15, b = bid>>9;
    const int tid = threadIdx.x;
    const int wave = tid>>6, lane = tid&63, quad = lane>>4, l15 = lane&15;
    const size_t row0 = (size_t)b*SEQ + n*CHUNK;
    const int col0 = h*D_HEAD;
    const float lnw = -__expf(td[h]);
    for (int it=0; it<4; ++it){
        int idx = tid + it*256;
        int row = idx>>3, c8 = (idx&7)*8;
        *(bf16x8*)&rS[row*72 + c8] = *(const bf16x8*)&rb[(row0+row)*D_MODEL + col0 + c8];
    }
    const bf16_t* stg = stT + (size_t)bid*4096;
    for (int it=0; it<2; ++it){
        int idx = tid + it*256;
        int row = idx>>3, c8 = (idx&7)*8;
        *(bf16x8*)&sS[row*72 + c8] = *(const bf16x8*)&stg[row*64 + c8];
    }
    __syncthreads();
    f32x4 acc[2][4];
    for (int i=0;i<2;++i) for (int j=0;j<4;++j) acc[i][j] = (f32x4){0.f,0.f,0.f,0.f};
    for (int kk=0; kk<2; ++kk){
        bf16x8 af[2], bfr[4];
        for (int i=0;i<2;++i) af[i] = *(const bf16x8*)&rS[(wave*32+i*16+l15)*72 + kk*32 + quad*8];
        for (int j=0;j<4;++j) bfr[j] = *(const bf16x8*)&sS[(j*16+l15)*72 + kk*32 + quad*8];
        for (int i=0;i<2;++i) for (int j=0;j<4;++j)
            acc[i][j] = __builtin_amdgcn_mfma_f32_16x16x32_bf16(af[i], bfr[j], acc[i][j], 0,0,0);
    }
    const float* sepb = sep + (size_t)bid*(CHUNK*D_HEAD);
    for (int i=0;i<2;++i) for (int j=0;j<4;++j) for (int e=0;e<4;++e){
        int si = wave*32 + i*16 + quad*4 + e;
        int d  = j*16 + l15;
        ap[si*68 + d] = acc[i][j][e]*__expf(lnw*(float)si) + sepb[si*D_HEAD + d];
    }
    __syncthreads();
    if (tid < 128){
        float s=0.f, q2=0.f;
        for (int d=0; d<64; ++d){ float v = ap[tid*68+d]; s += v; q2 += v*v; }
        float mu = s*(1.f/64.f);
        float var = q2*(1.f/64.f) - mu*mu;
        mu_s[tid] = mu; rs_s[tid] = rsqrtf(var + LN_EPS);
    }
    __syncthreads();
    for (int it=0; it<4; ++it){
        int idx = tid + it*256;
        int i = idx>>3, c8 = (idx&7)*8;
        float mu = mu_s[i], rs = rs_s[i];
        bf16x8 o;
        for (int q=0;q<8;++q){
            int d = c8+q;
            o[q] = (bf16_t)((ap[i*68+d]-mu)*rs*gx[col0+d] + bx[col0+d]);
        }
        *(bf16x8*)&att[(row0+i)*D_MODEL + col0 + c8] = o;
    }
}

// ---------------------------------------------------------------------------
// Launch. Workspace layout (requires ws_size >= 224 MiB), with aliasing:
//   [0,32)   rxb bf16        -> later sep f32 [0,64)
//   [32,64)  kxb bf16
//   [64,96)  vxb bf16        -> later U f32 [64,96) -> later att bf16 [64,96)
//   [96,104) WrT bf16        -> later stT bf16 [96,112)
//   [104,112) WkT, [112,120) WvT, [120,128) WoT (WoT alive to the end)
//   [128,160) rb, [160,192) kb, [192,224) vb   (bf16 GEMM outputs)
// ---------------------------------------------------------------------------
extern "C" void kernel_launch(void* const* d_in, const int* in_sizes, int n_in,
                              void* d_out, int out_size, void* d_ws, size_t ws_size,
                              hipStream_t stream) {
    const float* x   = (const float*)d_in[0];
    const float* tmr = (const float*)d_in[1];
    const float* tmk = (const float*)d_in[2];
    const float* tmv = (const float*)d_in[3];
    const float* Wk  = (const float*)d_in[4];
    const float* Wv  = (const float*)d_in[5];
    const float* Wr  = (const float*)d_in[6];
    const float* Wo  = (const float*)d_in[7];
    const float* td  = (const float*)d_in[8];
    const float* tf  = (const float*)d_in[9];
    const float* g1  = (const float*)d_in[10];
    const float* b1  = (const float*)d_in[11];
    const float* gx  = (const float*)d_in[12];
    const float* bx  = (const float*)d_in[13];

    float* out0 = (float*)d_out;                       // inputs + out
    float* out1 = out0 + (size_t)NTOK*D_MODEL;         // xn[:, -1, :]
    float* out2 = out1 + (size_t)BZ*D_MODEL;           // final state

    const size_t MB = 1ull<<20;
    char* ws = (char*)d_ws;
    bf16_t* rxb = (bf16_t*)(ws);
    bf16_t* kxb = (bf16_t*)(ws + 32*MB);
    bf16_t* vxb = (bf16_t*)(ws + 64*MB);
    bf16_t* WrT = (bf16_t*)(ws + 96*MB);
    bf16_t* WkT = (bf16_t*)(ws + 104*MB);
    bf16_t* WvT = (bf16_t*)(ws + 112*MB);
    bf16_t* WoT = (bf16_t*)(ws + 120*MB);
    bf16_t* rb  = (bf16_t*)(ws + 128*MB);
    bf16_t* kb  = (bf16_t*)(ws + 160*MB);
    bf16_t* vb  = (bf16_t*)(ws + 192*MB);
    float*  sep = (float*)(ws);                        // after rxb/kxb dead
    float*  U   = (float*)(ws + 64*MB);                // after vxb dead
    bf16_t* stT = (bf16_t*)(ws + 96*MB);               // after WrT/WkT dead
    bf16_t* att = (bf16_t*)(ws + 64*MB);               // after U dead

    k_ln_mix<<<NTOK, 256, 0, stream>>>(x, tmr, tmk, tmv, g1, b1, rxb, kxb, vxb, out1);

    dim3 gT(32, 32);
    k_wt<<<gT, 256, 0, stream>>>(Wr, WrT);
    k_wt<<<gT, 256, 0, stream>>>(Wk, WkT);
    k_wt<<<gT, 256, 0, stream>>>(Wv, WvT);
    k_wt<<<gT, 256, 0, stream>>>(Wo, WoT);

    dim3 gG(D_MODEL/128, NTOK/128);   // (16, 64)
    k_gemm_bt<1><<<gG, 256, 0, stream>>>(rxb, WrT, rb, nullptr, D_MODEL, D_MODEL);
    k_gemm_bt<1><<<gG, 256, 0, stream>>>(kxb, WkT, kb, nullptr, D_MODEL, D_MODEL);
    k_gemm_bt<1><<<gG, 256, 0, stream>>>(vxb, WvT, vb, nullptr, D_MODEL, D_MODEL);

    const int nblk = BZ*NC*N_HEADS;   // 2048
    k_chunk_att<<<nblk, 256, 0, stream>>>(rb, kb, vb, td, tf, sep);
    k_chunk_U  <<<nblk, 256, 0, stream>>>(kb, vb, td, U);
    k_scan     <<<BZ*N_HEADS, 256, 0, stream>>>(U, td, stT, out2);
    k_bias_ln  <<<nblk, 256, 0, stream>>>(rb, stT, sep, td, gx, bx, att);

    k_gemm_bt<0><<<gG, 256, 0, stream>>>(att, WoT, out0, x, D_MODEL, D_MODEL);
}

// Round 3
// 701.458 us; speedup vs baseline: 1.1861x; 1.1861x over previous
//
#include <hip/hip_runtime.h>

#define D_MODEL 2048
#define N_HEADS 32
#define D_HEAD  64
#define CHUNK   128
#define SEQ     2048
#define BZ      4
#define NC      16            // SEQ/CHUNK
#define NTOK    (BZ*SEQ)      // 8192
#define LN_EPS  1e-5f

typedef __bf16 bf16_t;
typedef bf16_t bf16x8 __attribute__((ext_vector_type(8)));
typedef float  f32x4  __attribute__((ext_vector_type(4)));

#define GLOBAL_AS __attribute__((address_space(1)))
#define LDS_AS    __attribute__((address_space(3)))

// ---------------------------------------------------------------------------
// K1: LayerNorm + token-shift time-mix -> rx,kx,vx (bf16). Also writes
// xn[:, -1, :] (output 1).
// ---------------------------------------------------------------------------
__global__ __launch_bounds__(256) void k_ln_mix(
    const float* __restrict__ x, const float* __restrict__ tmr,
    const float* __restrict__ tmk, const float* __restrict__ tmv,
    const float* __restrict__ g1, const float* __restrict__ b1,
    bf16_t* __restrict__ rxb, bf16_t* __restrict__ kxb, bf16_t* __restrict__ vxb,
    float* __restrict__ xn_last)
{
    __shared__ float sbuf[16];
    const int row = blockIdx.x;
    const int t = row & (SEQ-1);
    const int tid = threadIdx.x;
    const float4* xc4 = (const float4*)(x + (size_t)row*D_MODEL);
    float4 c0 = xc4[tid*2], c1 = xc4[tid*2+1];
    float4 p0 = {0,0,0,0}, p1 = {0,0,0,0};
    const bool hasprev = (t != 0);
    if (hasprev){
        const float4* xp4 = (const float4*)(x + (size_t)(row-1)*D_MODEL);
        p0 = xp4[tid*2]; p1 = xp4[tid*2+1];
    }
    float xc[8] = {c0.x,c0.y,c0.z,c0.w,c1.x,c1.y,c1.z,c1.w};
    float xp[8] = {p0.x,p0.y,p0.z,p0.w,p1.x,p1.y,p1.z,p1.w};
    float sc=0.f, qc=0.f, sp=0.f, qp=0.f;
    for (int q=0;q<8;++q){ sc+=xc[q]; qc+=xc[q]*xc[q]; sp+=xp[q]; qp+=xp[q]*xp[q]; }
    for (int o=1;o<64;o<<=1){
        sc += __shfl_xor(sc,o,64); qc += __shfl_xor(qc,o,64);
        sp += __shfl_xor(sp,o,64); qp += __shfl_xor(qp,o,64);
    }
    const int wave = tid>>6, lane = tid&63;
    if (lane==0){ sbuf[wave*4+0]=sc; sbuf[wave*4+1]=qc; sbuf[wave*4+2]=sp; sbuf[wave*4+3]=qp; }
    __syncthreads();
    sc = sbuf[0]+sbuf[4]+sbuf[8]+sbuf[12];
    qc = sbuf[1]+sbuf[5]+sbuf[9]+sbuf[13];
    sp = sbuf[2]+sbuf[6]+sbuf[10]+sbuf[14];
    qp = sbuf[3]+sbuf[7]+sbuf[11]+sbuf[15];
    const float inv = 1.f/(float)D_MODEL;
    float muc = sc*inv, varc = qc*inv - muc*muc;
    float rc  = rsqrtf(varc + LN_EPS);
    float mup = sp*inv, varp = qp*inv - mup*mup;
    float rp  = rsqrtf(varp + LN_EPS);
    bf16x8 rv, kv, vv;
    const int ci = tid*8;
    float xnl[8];
    for (int q=0;q<8;++q){
        int c = ci+q;
        float gg = g1[c], bb = b1[c];
        float xn = (xc[q]-muc)*rc*gg + bb;
        float sh = hasprev ? ((xp[q]-mup)*rp*gg + bb) : 0.f;
        float mr = tmr[c], mk = tmk[c], mv = tmv[c];
        rv[q] = (bf16_t)(xn*mr + (1.f-mr)*sh);
        kv[q] = (bf16_t)(xn*mk + (1.f-mk)*sh);
        vv[q] = (bf16_t)(xn*mv + (1.f-mv)*sh);
        xnl[q] = xn;
    }
    size_t base = (size_t)row*D_MODEL + ci;
    *(bf16x8*)&rxb[base] = rv;
    *(bf16x8*)&kxb[base] = kv;
    *(bf16x8*)&vxb[base] = vv;
    if (t == SEQ-1){
        int b = row >> 11;
        for (int q=0;q<8;++q) xn_last[(size_t)b*D_MODEL + ci + q] = xnl[q];
    }
}

// ---------------------------------------------------------------------------
// K2: batched transpose + f32->bf16: WT[z][n][k] = W_z[k][n]. z selects weight.
// ---------------------------------------------------------------------------
__global__ __launch_bounds__(256) void k_wt4(
    const float* __restrict__ W0, const float* __restrict__ W1,
    const float* __restrict__ W2, const float* __restrict__ W3,
    bf16_t* __restrict__ WTbase)
{
    __shared__ float tile[64][65];
    const int z = blockIdx.z;
    const float* W = (z==0)?W0:(z==1)?W1:(z==2)?W2:W3;
    bf16_t* WT = WTbase + (size_t)z*D_MODEL*D_MODEL;
    const int n0 = blockIdx.x*64, k0 = blockIdx.y*64;
    const int j = threadIdx.x & 63, i0 = threadIdx.x >> 6;
    for (int it=0; it<16; ++it){
        int i = i0 + it*4;
        tile[j][i] = W[(size_t)(k0+i)*D_MODEL + n0 + j];
    }
    __syncthreads();
    for (int it=0; it<16; ++it){
        int idx = threadIdx.x + it*256;
        int r = idx >> 6, c = idx & 63;
        WT[(size_t)(n0+r)*D_MODEL + k0 + c] = (bf16_t)tile[r][c];
    }
}

// ---------------------------------------------------------------------------
// K3 core: bf16 GEMM C = A(MxK) * B^T(NxK)^T. 128x128 tile, BK=64 as two
// independent 32-wide slabs (each slab keeps m97's unpadded 128x32 layout so
// global_load_lds stays wave-contiguous and ds_read bank behavior matches
// the measured m97 config). 2 barriers per 64-K -> half the drain events.
// ---------------------------------------------------------------------------
template<int OUT_BF16>
__device__ __forceinline__ void gemm_core(
    const bf16_t* __restrict__ A, const bf16_t* __restrict__ B,
    void* __restrict__ Cout, const float* __restrict__ resid,
    int N, int K, char* smem, int bx, int by)
{
    bf16_t* Sl[4] = { (bf16_t*)smem, (bf16_t*)(smem+8192),
                      (bf16_t*)(smem+16384), (bf16_t*)(smem+24576) }; // As0,As1,Bs0,Bs1
    const int tid = threadIdx.x;
    const int wave = tid>>6, lane = tid&63;
    const int quad = lane>>4, l15 = lane&15;
    const int wm = (wave>>1)*64, wn = (wave&1)*64;
    const size_t arow0 = (size_t)by*128;
    const size_t brow0 = (size_t)bx*128;
    const int r0 = tid>>2, ca = (tid&3)*8;
    f32x4 acc[4][4];
    for (int i=0;i<4;++i) for (int j=0;j<4;++j) acc[i][j] = (f32x4){0.f,0.f,0.f,0.f};
    for (int k0=0; k0<K; k0+=64){
        #pragma unroll
        for (int it=0; it<2; ++it){
            int s   = tid + it*256;
            int row = r0 + it*64;
            const bf16_t* ga = &A[(arow0+row)*K + k0 + ca];
            const bf16_t* gb = &B[(brow0+row)*K + k0 + ca];
            __builtin_amdgcn_global_load_lds((const GLOBAL_AS void*)(ga),    (LDS_AS void*)&Sl[0][s*8], 16, 0, 0);
            __builtin_amdgcn_global_load_lds((const GLOBAL_AS void*)(ga+32), (LDS_AS void*)&Sl[1][s*8], 16, 0, 0);
            __builtin_amdgcn_global_load_lds((const GLOBAL_AS void*)(gb),    (LDS_AS void*)&Sl[2][s*8], 16, 0, 0);
            __builtin_amdgcn_global_load_lds((const GLOBAL_AS void*)(gb+32), (LDS_AS void*)&Sl[3][s*8], 16, 0, 0);
        }
        __syncthreads();
        #pragma unroll
        for (int slab=0; slab<2; ++slab){
            const bf16_t* As = Sl[slab];
            const bf16_t* Bs = Sl[2+slab];
            bf16x8 af[4], bfr[4];
            for (int i=0;i<4;++i){
                af[i]  = *(const bf16x8*)&As[(wm+i*16+l15)*32 + quad*8];
                bfr[i] = *(const bf16x8*)&Bs[(wn+i*16+l15)*32 + quad*8];
            }
            for (int i=0;i<4;++i)
                for (int j=0;j<4;++j)
                    acc[i][j] = __builtin_amdgcn_mfma_f32_16x16x32_bf16(af[i], bfr[j], acc[i][j], 0,0,0);
        }
        __syncthreads();
    }
    if (OUT_BF16){
        // repack through LDS -> 16B coalesced stores (kills 2x write amplification)
        bf16_t* Rp = (bf16_t*)smem;   // [128][72]
        for (int jh=0; jh<2; ++jh){
            if ((wave&1) == jh){
                for (int i=0;i<4;++i) for (int j=0;j<4;++j) for (int e=0;e<4;++e)
                    Rp[(wm+i*16+quad*4+e)*72 + j*16 + l15] = (bf16_t)acc[i][j][e];
            }
            __syncthreads();
            for (int it=0; it<4; ++it){
                int idx = tid + it*256;
                int row = idx>>3, c8 = (idx&7)*8;
                *(bf16x8*)&((bf16_t*)Cout)[(arow0+row)*(size_t)N + brow0 + jh*64 + c8] =
                    *(const bf16x8*)&Rp[row*72 + c8];
            }
            __syncthreads();
        }
    } else {
        for (int i=0;i<4;++i) for (int j=0;j<4;++j) for (int e=0;e<4;++e){
            size_t r = arow0 + wm + i*16 + quad*4 + e;
            size_t c = brow0 + wn + j*16 + l15;
            ((float*)Cout)[r*(size_t)N + c] = resid[r*(size_t)N + c] + acc[i][j][e];
        }
    }
}

// batched r/k/v GEMM: z selects A/B/C by fixed stride
__global__ __launch_bounds__(256) void k_gemm_rkv(
    const bf16_t* __restrict__ Abase, const bf16_t* __restrict__ Bbase,
    bf16_t* __restrict__ Cbase)
{
    __shared__ __align__(16) char smem[32768];
    const int z = blockIdx.z;
    const bf16_t* A = Abase + (size_t)z*NTOK*D_MODEL;
    const bf16_t* B = Bbase + (size_t)z*D_MODEL*D_MODEL;
    bf16_t*       C = Cbase + (size_t)z*NTOK*D_MODEL;
    gemm_core<1>(A, B, (void*)C, nullptr, D_MODEL, D_MODEL, smem, blockIdx.x, blockIdx.y);
}

__global__ __launch_bounds__(256) void k_gemm_out(
    const bf16_t* __restrict__ A, const bf16_t* __restrict__ B,
    float* __restrict__ C, const float* __restrict__ resid)
{
    __shared__ __align__(16) char smem[32768];
    gemm_core<0>(A, B, (void*)C, resid, D_MODEL, D_MODEL, smem, blockIdx.x, blockIdx.y);
}

// ---------------------------------------------------------------------------
// K4b: per (b,chunk,h): U[e][d] = sum_j k[j][e] * w^(C-1-j) * v[j][d]
// ---------------------------------------------------------------------------
__global__ __launch_bounds__(256) void k_chunk_U(
    const bf16_t* __restrict__ kb, const bf16_t* __restrict__ vb,
    const float* __restrict__ td, float* __restrict__ U)
{
    __shared__ __align__(16) bf16_t kT[64*136];
    __shared__ __align__(16) bf16_t vT[64*136];
    const int bid = blockIdx.x;
    const int h = bid & 31, n = (bid>>5)&15, b = bid>>9;
    const int tid = threadIdx.x;
    const int wave = tid>>6, lane = tid&63, quad = lane>>4, l15 = lane&15;
    const size_t row0 = (size_t)b*SEQ + n*CHUNK;
    const int col0 = h*D_HEAD;
    const float lnw = -__expf(td[h]);
    for (int it=0; it<4; ++it){
        int idx = tid + it*256;
        int row = idx>>3, c8 = (idx&7)*8;
        float wj = __expf(lnw * (float)(CHUNK-1-row));
        bf16x8 kv = *(const bf16x8*)&kb[(row0+row)*D_MODEL + col0 + c8];
        bf16x8 vv = *(const bf16x8*)&vb[(row0+row)*D_MODEL + col0 + c8];
        for (int q=0;q<8;++q){
            kT[(c8+q)*136 + row] = (bf16_t)((float)kv[q] * wj);
            vT[(c8+q)*136 + row] = vv[q];
        }
    }
    __syncthreads();
    f32x4 accU[4];
    for (int j=0;j<4;++j) accU[j] = (f32x4){0.f,0.f,0.f,0.f};
    for (int kk=0; kk<4; ++kk){
        bf16x8 af = *(const bf16x8*)&kT[(wave*16+l15)*136 + kk*32 + quad*8];
        bf16x8 bfr[4];
        for (int j=0;j<4;++j) bfr[j] = *(const bf16x8*)&vT[(j*16+l15)*136 + kk*32 + quad*8];
        for (int j=0;j<4;++j)
            accU[j] = __builtin_amdgcn_mfma_f32_16x16x32_bf16(af, bfr[j], accU[j], 0,0,0);
    }
    float* Ub = U + (size_t)bid*(D_HEAD*D_HEAD);
    for (int j=0;j<4;++j) for (int e=0;e<4;++e){
        int ei = wave*16 + quad*4 + e;
        int d  = j*16 + l15;
        Ub[ei*D_HEAD + d] = accU[j][e];
    }
}

// ---------------------------------------------------------------------------
// K5: sequential prefix over chunks (per b,h).
// ---------------------------------------------------------------------------
__global__ __launch_bounds__(256) void k_scan(
    const float* __restrict__ U, const float* __restrict__ td,
    bf16_t* __restrict__ stT, float* __restrict__ outState)
{
    const int bh = blockIdx.x;
    const int h = bh & 31, b = bh >> 5;
    const int tid = threadIdx.x;
    const float lnw = -__expf(td[h]);
    const float wC  =  __expf(lnw * (float)CHUNK);
    float st[16];
    for (int q=0;q<16;++q) st[q] = 0.f;
    for (int n=0;n<NC;++n){
        size_t base = ((size_t)((b*NC + n)*N_HEADS + h))*4096;
        for (int q=0;q<16;++q){
            int f = tid + q*256;
            int e = f>>6, d = f&63;
            stT[base + d*64 + e] = (bf16_t)st[q];
            st[q] = st[q]*wC + U[base + f];
        }
    }
    size_t ob = ((size_t)(b*N_HEADS + h))*4096;
    for (int q=0;q<16;++q) outState[ob + tid + q*256] = st[q];
}

// ---------------------------------------------------------------------------
// K6: fused per (b,chunk,h): S=(r k^T)*mask -> P=S v (slice-staged) ->
// bias=(r state)*w^i -> LN over d_head (in-register shuffle) -> att bf16.
// No sep round-trip, no rb re-read.
// ---------------------------------------------------------------------------
__global__ __launch_bounds__(256) void k_att_fused(
    const bf16_t* __restrict__ rb, const bf16_t* __restrict__ kb, const bf16_t* __restrict__ vb,
    const bf16_t* __restrict__ stT, const float* __restrict__ td, const float* __restrict__ tf,
    const float* __restrict__ gx, const float* __restrict__ bx,
    bf16_t* __restrict__ att)
{
    __shared__ __align__(16) char smem[63488];
    bf16_t* rS  = (bf16_t*)smem;               // [128][72]
    bf16_t* kS  = (bf16_t*)(smem + 18432);     // [128][72]; later Sst [128][40], att_s [128][72]
    bf16_t* vT  = (bf16_t*)(smem + 36864);     // [64][136]
    bf16_t* sS  = (bf16_t*)(smem + 54272);     // [64][72]
    bf16_t* Sst = kS;
    bf16_t* att_s = kS;
    const int bid = blockIdx.x;
    const int h = bid & 31, n = (bid>>5)&15, b = bid>>9;
    const int tid = threadIdx.x;
    const int wave = tid>>6, lane = tid&63, quad = lane>>4, l15 = lane&15;
    const size_t row0 = (size_t)b*SEQ + n*CHUNK;
    const int col0 = h*D_HEAD;
    const float lnw = -__expf(td[h]);
    const float u   =  __expf(tf[h]);
    for (int it=0; it<4; ++it){
        int idx = tid + it*256;
        int row = idx>>3, c8 = (idx&7)*8;
        *(bf16x8*)&rS[row*72 + c8] = *(const bf16x8*)&rb[(row0+row)*D_MODEL + col0 + c8];
        *(bf16x8*)&kS[row*72 + c8] = *(const bf16x8*)&kb[(row0+row)*D_MODEL + col0 + c8];
        bf16x8 vv = *(const bf16x8*)&vb[(row0+row)*D_MODEL + col0 + c8];
        for (int q=0;q<8;++q) vT[(c8+q)*136 + row] = vv[q];
    }
    const bf16_t* stg = stT + (size_t)bid*4096;
    for (int it=0; it<2; ++it){
        int idx = tid + it*256;
        int row = idx>>3, c8 = (idx&7)*8;
        *(bf16x8*)&sS[row*72 + c8] = *(const bf16x8*)&stg[row*64 + c8];
    }
    __syncthreads();
    // --- S = r k^T (full 128x128 in registers)
    f32x4 accS[2][8];
    for (int i=0;i<2;++i) for (int j=0;j<8;++j) accS[i][j] = (f32x4){0.f,0.f,0.f,0.f};
    for (int kk=0; kk<2; ++kk){
        bf16x8 af[2], bfr[8];
        for (int i=0;i<2;++i) af[i] = *(const bf16x8*)&rS[(wave*32+i*16+l15)*72 + kk*32 + quad*8];
        for (int j=0;j<8;++j) bfr[j] = *(const bf16x8*)&kS[(j*16+l15)*72 + kk*32 + quad*8];
        for (int i=0;i<2;++i) for (int j=0;j<8;++j)
            accS[i][j] = __builtin_amdgcn_mfma_f32_16x16x32_bf16(af[i], bfr[j], accS[i][j], 0,0,0);
    }
    __syncthreads();   // kS dead; Sst overlays it
    // --- P = (S*mask) v, staged 32 columns at a time
    f32x4 accP[2][4];
    for (int i=0;i<2;++i) for (int j=0;j<4;++j) accP[i][j] = (f32x4){0.f,0.f,0.f,0.f};
    for (int kk=0; kk<4; ++kk){
        for (int i=0;i<2;++i) for (int jj=0;jj<2;++jj) for (int e=0;e<4;++e){
            int si = wave*32 + i*16 + quad*4 + e;
            int sj = kk*32 + jj*16 + l15;
            float m;
            if (si > sj)       m = __expf(lnw * (float)(si-sj-1));
            else if (si == sj) m = u;
            else               m = 0.f;
            Sst[si*40 + jj*16 + l15] = (bf16_t)(accS[i][kk*2+jj][e] * m);
        }
        __syncthreads();
        bf16x8 af[2], bfr[4];
        for (int i=0;i<2;++i) af[i] = *(const bf16x8*)&Sst[(wave*32+i*16+l15)*40 + quad*8];
        for (int j=0;j<4;++j) bfr[j] = *(const bf16x8*)&vT[(j*16+l15)*136 + kk*32 + quad*8];
        for (int i=0;i<2;++i) for (int j=0;j<4;++j)
            accP[i][j] = __builtin_amdgcn_mfma_f32_16x16x32_bf16(af[i], bfr[j], accP[i][j], 0,0,0);
        __syncthreads();
    }
    // --- bias = r @ state (state staged transposed: sS[d][e])
    f32x4 accB[2][4];
    for (int i=0;i<2;++i) for (int j=0;j<4;++j) accB[i][j] = (f32x4){0.f,0.f,0.f,0.f};
    for (int kk=0; kk<2; ++kk){
        bf16x8 af[2], bfr[4];
        for (int i=0;i<2;++i) af[i] = *(const bf16x8*)&rS[(wave*32+i*16+l15)*72 + kk*32 + quad*8];
        for (int j=0;j<4;++j) bfr[j] = *(const bf16x8*)&sS[(j*16+l15)*72 + kk*32 + quad*8];
        for (int i=0;i<2;++i) for (int j=0;j<4;++j)
            accB[i][j] = __builtin_amdgcn_mfma_f32_16x16x32_bf16(af[i], bfr[j], accB[i][j], 0,0,0);
    }
    // --- combine + in-register LayerNorm over d (64 values spread over 16 lanes x 4 regs)
    float pre[2][4][4];
    float mu_r[2][4], rs_r[2][4];
    for (int i=0;i<2;++i) for (int e=0;e<4;++e){
        int si = wave*32 + i*16 + quad*4 + e;
        float wsi = __expf(lnw * (float)si);
        float s = 0.f, q2 = 0.f;
        for (int j=0;j<4;++j){
            float v = accP[i][j][e] + accB[i][j][e]*wsi;
            pre[i][j][e] = v;
            s += v; q2 += v*v;
        }
        for (int o=1;o<16;o<<=1){ s += __shfl_xor(s,o,64); q2 += __shfl_xor(q2,o,64); }
        float mu = s*(1.f/64.f);
        float var = q2*(1.f/64.f) - mu*mu;
        mu_r[i][e] = mu; rs_r[i][e] = rsqrtf(var + LN_EPS);
    }
    float gxv[4], bxv[4];
    for (int j=0;j<4;++j){ gxv[j] = gx[col0 + j*16 + l15]; bxv[j] = bx[col0 + j*16 + l15]; }
    for (int i=0;i<2;++i) for (int j=0;j<4;++j) for (int e=0;e<4;++e){
        int si = wave*32 + i*16 + quad*4 + e;
        att_s[si*72 + j*16 + l15] = (bf16_t)((pre[i][j][e]-mu_r[i][e])*rs_r[i][e]*gxv[j] + bxv[j]);
    }
    __syncthreads();
    for (int it=0; it<4; ++it){
        int idx = tid + it*256;
        int row = idx>>3, c8 = (idx&7)*8;
        *(bf16x8*)&att[(row0+row)*D_MODEL + col0 + c8] = *(const bf16x8*)&att_s[row*72 + c8];
    }
}

// ---------------------------------------------------------------------------
// Launch. Workspace (>= 224 MiB), aliasing:
//   [0,32)    rxb bf16   -> U f32 (after rkv GEMM)
//   [32,64)   kxb bf16   -> stT bf16
//   [64,96)   vxb bf16   -> att bf16
//   [96,128)  WT[4] bf16 (Wr,Wk,Wv,Wo transposed; Wo alive to end)
//   [128,160) rb, [160,192) kb, [192,224) vb
// ---------------------------------------------------------------------------
extern "C" void kernel_launch(void* const* d_in, const int* in_sizes, int n_in,
                              void* d_out, int out_size, void* d_ws, size_t ws_size,
                              hipStream_t stream) {
    const float* x   = (const float*)d_in[0];
    const float* tmr = (const float*)d_in[1];
    const float* tmk = (const float*)d_in[2];
    const float* tmv = (const float*)d_in[3];
    const float* Wk  = (const float*)d_in[4];
    const float* Wv  = (const float*)d_in[5];
    const float* Wr  = (const float*)d_in[6];
    const float* Wo  = (const float*)d_in[7];
    const float* td  = (const float*)d_in[8];
    const float* tf  = (const float*)d_in[9];
    const float* g1  = (const float*)d_in[10];
    const float* b1  = (const float*)d_in[11];
    const float* gx  = (const float*)d_in[12];
    const float* bx  = (const float*)d_in[13];

    float* out0 = (float*)d_out;
    float* out1 = out0 + (size_t)NTOK*D_MODEL;
    float* out2 = out1 + (size_t)BZ*D_MODEL;

    const size_t MB = 1ull<<20;
    char* ws = (char*)d_ws;
    bf16_t* rxb = (bf16_t*)(ws);
    bf16_t* kxb = (bf16_t*)(ws + 32*MB);
    bf16_t* vxb = (bf16_t*)(ws + 64*MB);
    bf16_t* WTb = (bf16_t*)(ws + 96*MB);          // 4 x 8MB: Wr,Wk,Wv,Wo
    bf16_t* WoT = (bf16_t*)(ws + 120*MB);
    bf16_t* rb  = (bf16_t*)(ws + 128*MB);
    float*  U   = (float*)(ws);                   // after rxb dead
    bf16_t* stT = (bf16_t*)(ws + 32*MB);          // after kxb dead
    bf16_t* att = (bf16_t*)(ws + 64*MB);          // after vxb dead
    bf16_t* kb  = (bf16_t*)(ws + 160*MB);
    bf16_t* vb  = (bf16_t*)(ws + 192*MB);

    k_ln_mix<<<NTOK, 256, 0, stream>>>(x, tmr, tmk, tmv, g1, b1, rxb, kxb, vxb, out1);

    dim3 gT(32, 32, 4);
    k_wt4<<<gT, 256, 0, stream>>>(Wr, Wk, Wv, Wo, WTb);

    dim3 gG3(D_MODEL/128, NTOK/128, 3);   // (16, 64, 3)
    k_gemm_rkv<<<gG3, 256, 0, stream>>>(rxb, WTb, rb);

    const int nblk = BZ*NC*N_HEADS;   // 2048
    k_chunk_U <<<nblk, 256, 0, stream>>>(kb, vb, td, U);
    k_scan    <<<BZ*N_HEADS, 256, 0, stream>>>(U, td, stT, out2);
    k_att_fused<<<nblk, 256, 0, stream>>>(rb, kb, vb, stT, td, tf, gx, bx, att);

    dim3 gG(D_MODEL/128, NTOK/128);
    k_gemm_out<<<gG, 256, 0, stream>>>(att, WoT, out0, x);
}

// Round 4
// 699.066 us; speedup vs baseline: 1.1901x; 1.0034x over previous
//
#include <hip/hip_runtime.h>

#define D_MODEL 2048
#define N_HEADS 32
#define D_HEAD  64
#define CHUNK   128
#define SEQ     2048
#define BZ      4
#define NC      16            // SEQ/CHUNK
#define NTOK    (BZ*SEQ)      // 8192
#define LN_EPS  1e-5f

typedef __bf16 bf16_t;
typedef bf16_t bf16x8 __attribute__((ext_vector_type(8)));
typedef float  f32x4  __attribute__((ext_vector_type(4)));
typedef float  f32x16 __attribute__((ext_vector_type(16)));

#define GLOBAL_AS __attribute__((address_space(1)))
#define LDS_AS    __attribute__((address_space(3)))

// ---------------------------------------------------------------------------
// K1: LayerNorm + token-shift time-mix -> rx,kx,vx (bf16). Also writes
// xn[:, -1, :] (output 1).
// ---------------------------------------------------------------------------
__global__ __launch_bounds__(256) void k_ln_mix(
    const float* __restrict__ x, const float* __restrict__ tmr,
    const float* __restrict__ tmk, const float* __restrict__ tmv,
    const float* __restrict__ g1, const float* __restrict__ b1,
    bf16_t* __restrict__ rxb, bf16_t* __restrict__ kxb, bf16_t* __restrict__ vxb,
    float* __restrict__ xn_last)
{
    __shared__ float sbuf[16];
    const int row = blockIdx.x;
    const int t = row & (SEQ-1);
    const int tid = threadIdx.x;
    const float4* xc4 = (const float4*)(x + (size_t)row*D_MODEL);
    float4 c0 = xc4[tid*2], c1 = xc4[tid*2+1];
    float4 p0 = {0,0,0,0}, p1 = {0,0,0,0};
    const bool hasprev = (t != 0);
    if (hasprev){
        const float4* xp4 = (const float4*)(x + (size_t)(row-1)*D_MODEL);
        p0 = xp4[tid*2]; p1 = xp4[tid*2+1];
    }
    float xc[8] = {c0.x,c0.y,c0.z,c0.w,c1.x,c1.y,c1.z,c1.w};
    float xp[8] = {p0.x,p0.y,p0.z,p0.w,p1.x,p1.y,p1.z,p1.w};
    float sc=0.f, qc=0.f, sp=0.f, qp=0.f;
    for (int q=0;q<8;++q){ sc+=xc[q]; qc+=xc[q]*xc[q]; sp+=xp[q]; qp+=xp[q]*xp[q]; }
    for (int o=1;o<64;o<<=1){
        sc += __shfl_xor(sc,o,64); qc += __shfl_xor(qc,o,64);
        sp += __shfl_xor(sp,o,64); qp += __shfl_xor(qp,o,64);
    }
    const int wave = tid>>6, lane = tid&63;
    if (lane==0){ sbuf[wave*4+0]=sc; sbuf[wave*4+1]=qc; sbuf[wave*4+2]=sp; sbuf[wave*4+3]=qp; }
    __syncthreads();
    sc = sbuf[0]+sbuf[4]+sbuf[8]+sbuf[12];
    qc = sbuf[1]+sbuf[5]+sbuf[9]+sbuf[13];
    sp = sbuf[2]+sbuf[6]+sbuf[10]+sbuf[14];
    qp = sbuf[3]+sbuf[7]+sbuf[11]+sbuf[15];
    const float inv = 1.f/(float)D_MODEL;
    float muc = sc*inv, varc = qc*inv - muc*muc;
    float rc  = rsqrtf(varc + LN_EPS);
    float mup = sp*inv, varp = qp*inv - mup*mup;
    float rp  = rsqrtf(varp + LN_EPS);
    bf16x8 rv, kv, vv;
    const int ci = tid*8;
    float xnl[8];
    for (int q=0;q<8;++q){
        int c = ci+q;
        float gg = g1[c], bb = b1[c];
        float xn = (xc[q]-muc)*rc*gg + bb;
        float sh = hasprev ? ((xp[q]-mup)*rp*gg + bb) : 0.f;
        float mr = tmr[c], mk = tmk[c], mv = tmv[c];
        rv[q] = (bf16_t)(xn*mr + (1.f-mr)*sh);
        kv[q] = (bf16_t)(xn*mk + (1.f-mk)*sh);
        vv[q] = (bf16_t)(xn*mv + (1.f-mv)*sh);
        xnl[q] = xn;
    }
    size_t base = (size_t)row*D_MODEL + ci;
    *(bf16x8*)&rxb[base] = rv;
    *(bf16x8*)&kxb[base] = kv;
    *(bf16x8*)&vxb[base] = vv;
    if (t == SEQ-1){
        int b = row >> 11;
        for (int q=0;q<8;++q) xn_last[(size_t)b*D_MODEL + ci + q] = xnl[q];
    }
}

// ---------------------------------------------------------------------------
// K2: batched transpose + f32->bf16: WT[z][n][k] = W_z[k][n].
// ---------------------------------------------------------------------------
__global__ __launch_bounds__(256) void k_wt4(
    const float* __restrict__ W0, const float* __restrict__ W1,
    const float* __restrict__ W2, const float* __restrict__ W3,
    bf16_t* __restrict__ WTbase)
{
    __shared__ float tile[64][65];
    const int z = blockIdx.z;
    const float* W = (z==0)?W0:(z==1)?W1:(z==2)?W2:W3;
    bf16_t* WT = WTbase + (size_t)z*D_MODEL*D_MODEL;
    const int n0 = blockIdx.x*64, k0 = blockIdx.y*64;
    const int j = threadIdx.x & 63, i0 = threadIdx.x >> 6;
    for (int it=0; it<16; ++it){
        int i = i0 + it*4;
        tile[j][i] = W[(size_t)(k0+i)*D_MODEL + n0 + j];
    }
    __syncthreads();
    for (int it=0; it<16; ++it){
        int idx = threadIdx.x + it*256;
        int r = idx >> 6, c = idx & 63;
        WT[(size_t)(n0+r)*D_MODEL + k0 + c] = (bf16_t)tile[r][c];
    }
}

// ---------------------------------------------------------------------------
// XCD-aware swizzle for a (16, 64) tile grid. HW round-robins blocks to XCDs
// by linear id (%8). Remap so XCD p owns y-rows with y%8==p: its consecutive
// blocks walk x at fixed y -> the A-tile is fetched by ONE XCD and stays
// L2-hot across its 16 x-blocks. B (24 MB) is L3-resident.
// ---------------------------------------------------------------------------
__device__ __forceinline__ void xcd_swizzle_16x64(int& bx, int& by)
{
    int id = blockIdx.y*16 + blockIdx.x;    // [0,1024)
    int p  = id & 7;
    int n  = id >> 3;                        // per-XCD sequence index
    bx = n & 15;
    by = ((n >> 4) << 3) | p;
}

// ---------------------------------------------------------------------------
// K3 core: bf16 GEMM C = A(MxK) * B^T(NxK)^T. 128x128 tile, BK=64 as two
// independent 32-wide slabs (m97-style unpadded layout so global_load_lds
// stays wave-contiguous). Compute: mfma_f32_32x32x16_bf16, 2x2 32x32 blocks
// per wave (half the MFMA instructions of the 16x16x32 version, 17% less
// matrix-pipe time per FLOP).
// C/D layout (HW-verified m74/m101): col=lane&31, row=(reg&3)+8*(reg>>2)+4*(lane>>5).
// ---------------------------------------------------------------------------
template<int OUT_BF16>
__device__ __forceinline__ void gemm_core(
    const bf16_t* __restrict__ A, const bf16_t* __restrict__ B,
    void* __restrict__ Cout, const float* __restrict__ resid,
    int N, int K, char* smem, int bx, int by)
{
    bf16_t* Sl[4] = { (bf16_t*)smem, (bf16_t*)(smem+8192),
                      (bf16_t*)(smem+16384), (bf16_t*)(smem+24576) }; // As0,As1,Bs0,Bs1
    const int tid = threadIdx.x;
    const int wave = tid>>6, lane = tid&63;
    const int l31 = lane&31, half = lane>>5;
    const int wm = (wave>>1)*64, wn = (wave&1)*64;
    const size_t arow0 = (size_t)by*128;
    const size_t brow0 = (size_t)bx*128;
    const int r0 = tid>>2, ca = (tid&3)*8;
    f32x16 acc[2][2];
    for (int i=0;i<2;++i) for (int j=0;j<2;++j)
        for (int e=0;e<16;++e) acc[i][j][e] = 0.f;
    for (int k0=0; k0<K; k0+=64){
        #pragma unroll
        for (int it=0; it<2; ++it){
            int s   = tid + it*256;
            int row = r0 + it*64;
            const bf16_t* ga = &A[(arow0+row)*K + k0 + ca];
            const bf16_t* gb = &B[(brow0+row)*K + k0 + ca];
            __builtin_amdgcn_global_load_lds((const GLOBAL_AS void*)(ga),    (LDS_AS void*)&Sl[0][s*8], 16, 0, 0);
            __builtin_amdgcn_global_load_lds((const GLOBAL_AS void*)(ga+32), (LDS_AS void*)&Sl[1][s*8], 16, 0, 0);
            __builtin_amdgcn_global_load_lds((const GLOBAL_AS void*)(gb),    (LDS_AS void*)&Sl[2][s*8], 16, 0, 0);
            __builtin_amdgcn_global_load_lds((const GLOBAL_AS void*)(gb+32), (LDS_AS void*)&Sl[3][s*8], 16, 0, 0);
        }
        __syncthreads();
        #pragma unroll
        for (int slab=0; slab<2; ++slab){
            const bf16_t* As = Sl[slab];
            const bf16_t* Bs = Sl[2+slab];
            // A-frag: lane holds A[m=wm+mb*32+l31][k=ks*16+half*8 + j], j<8
            bf16x8 af[2][2], bfr[2][2];   // [ks][mb/nb]
            #pragma unroll
            for (int ks=0; ks<2; ++ks)
                #pragma unroll
                for (int mb=0; mb<2; ++mb){
                    af[ks][mb]  = *(const bf16x8*)&As[(wm+mb*32+l31)*32 + ks*16 + half*8];
                    bfr[ks][mb] = *(const bf16x8*)&Bs[(wn+mb*32+l31)*32 + ks*16 + half*8];
                }
            #pragma unroll
            for (int ks=0; ks<2; ++ks)
                #pragma unroll
                for (int mb=0; mb<2; ++mb)
                    #pragma unroll
                    for (int nb=0; nb<2; ++nb)
                        acc[mb][nb] = __builtin_amdgcn_mfma_f32_32x32x16_bf16(
                            af[ks][mb], bfr[ks][nb], acc[mb][nb], 0,0,0);
        }
        __syncthreads();
    }
    if (OUT_BF16){
        // repack through LDS -> 16B coalesced stores
        bf16_t* Rp = (bf16_t*)smem;   // [128][72]
        #pragma unroll
        for (int jh=0; jh<2; ++jh){
            if ((wave&1) == jh){
                #pragma unroll
                for (int mb=0;mb<2;++mb)
                    #pragma unroll
                    for (int nb=0;nb<2;++nb)
                        #pragma unroll
                        for (int reg=0;reg<16;++reg){
                            int rrow = wm + mb*32 + (reg&3) + 8*(reg>>2) + 4*half;
                            Rp[rrow*72 + nb*32 + l31] = (bf16_t)acc[mb][nb][reg];
                        }
            }
            __syncthreads();
            for (int it=0; it<4; ++it){
                int idx = tid + it*256;
                int row = idx>>3, c8 = (idx&7)*8;
                *(bf16x8*)&((bf16_t*)Cout)[(arow0+row)*(size_t)N + brow0 + jh*64 + c8] =
                    *(const bf16x8*)&Rp[row*72 + c8];
            }
            __syncthreads();
        }
    } else {
        #pragma unroll
        for (int mb=0;mb<2;++mb)
            #pragma unroll
            for (int nb=0;nb<2;++nb)
                #pragma unroll
                for (int reg=0;reg<16;++reg){
                    size_t r = arow0 + wm + mb*32 + (reg&3) + 8*(reg>>2) + 4*half;
                    size_t c = brow0 + wn + nb*32 + l31;
                    ((float*)Cout)[r*(size_t)N + c] = resid[r*(size_t)N + c] + acc[mb][nb][reg];
                }
    }
}

// batched r/k/v GEMM: z selects A/B/C by fixed stride
__global__ __launch_bounds__(256) void k_gemm_rkv(
    const bf16_t* __restrict__ Abase, const bf16_t* __restrict__ Bbase,
    bf16_t* __restrict__ Cbase)
{
    __shared__ __align__(16) char smem[32768];
    const int z = blockIdx.z;
    const bf16_t* A = Abase + (size_t)z*NTOK*D_MODEL;
    const bf16_t* B = Bbase + (size_t)z*D_MODEL*D_MODEL;
    bf16_t*       C = Cbase + (size_t)z*NTOK*D_MODEL;
    int bx, by; xcd_swizzle_16x64(bx, by);
    gemm_core<1>(A, B, (void*)C, nullptr, D_MODEL, D_MODEL, smem, bx, by);
}

__global__ __launch_bounds__(256) void k_gemm_out(
    const bf16_t* __restrict__ A, const bf16_t* __restrict__ B,
    float* __restrict__ C, const float* __restrict__ resid)
{
    __shared__ __align__(16) char smem[32768];
    int bx, by; xcd_swizzle_16x64(bx, by);
    gemm_core<0>(A, B, (void*)C, resid, D_MODEL, D_MODEL, smem, bx, by);
}

// ---------------------------------------------------------------------------
// K4b: per (b,chunk,h): U[e][d] = sum_j k[j][e] * w^(C-1-j) * v[j][d]
// ---------------------------------------------------------------------------
__global__ __launch_bounds__(256) void k_chunk_U(
    const bf16_t* __restrict__ kb, const bf16_t* __restrict__ vb,
    const float* __restrict__ td, float* __restrict__ U)
{
    __shared__ __align__(16) bf16_t kT[64*136];
    __shared__ __align__(16) bf16_t vT[64*136];
    const int bid = blockIdx.x;
    const int h = bid & 31, n = (bid>>5)&15, b = bid>>9;
    const int tid = threadIdx.x;
    const int wave = tid>>6, lane = tid&63, quad = lane>>4, l15 = lane&15;
    const size_t row0 = (size_t)b*SEQ + n*CHUNK;
    const int col0 = h*D_HEAD;
    const float lnw = -__expf(td[h]);
    for (int it=0; it<4; ++it){
        int idx = tid + it*256;
        int row = idx>>3, c8 = (idx&7)*8;
        float wj = __expf(lnw * (float)(CHUNK-1-row));
        bf16x8 kv = *(const bf16x8*)&kb[(row0+row)*D_MODEL + col0 + c8];
        bf16x8 vv = *(const bf16x8*)&vb[(row0+row)*D_MODEL + col0 + c8];
        for (int q=0;q<8;++q){
            kT[(c8+q)*136 + row] = (bf16_t)((float)kv[q] * wj);
            vT[(c8+q)*136 + row] = vv[q];
        }
    }
    __syncthreads();
    f32x4 accU[4];
    for (int j=0;j<4;++j) accU[j] = (f32x4){0.f,0.f,0.f,0.f};
    for (int kk=0; kk<4; ++kk){
        bf16x8 af = *(const bf16x8*)&kT[(wave*16+l15)*136 + kk*32 + quad*8];
        bf16x8 bfr[4];
        for (int j=0;j<4;++j) bfr[j] = *(const bf16x8*)&vT[(j*16+l15)*136 + kk*32 + quad*8];
        for (int j=0;j<4;++j)
            accU[j] = __builtin_amdgcn_mfma_f32_16x16x32_bf16(af, bfr[j], accU[j], 0,0,0);
    }
    float* Ub = U + (size_t)bid*(D_HEAD*D_HEAD);
    for (int j=0;j<4;++j) for (int e=0;e<4;++e){
        int ei = wave*16 + quad*4 + e;
        int d  = j*16 + l15;
        Ub[ei*D_HEAD + d] = accU[j][e];
    }
}

// ---------------------------------------------------------------------------
// K5: sequential prefix over chunks (per b,h).
// ---------------------------------------------------------------------------
__global__ __launch_bounds__(256) void k_scan(
    const float* __restrict__ U, const float* __restrict__ td,
    bf16_t* __restrict__ stT, float* __restrict__ outState)
{
    const int bh = blockIdx.x;
    const int h = bh & 31, b = bh >> 5;
    const int tid = threadIdx.x;
    const float lnw = -__expf(td[h]);
    const float wC  =  __expf(lnw * (float)CHUNK);
    float st[16];
    for (int q=0;q<16;++q) st[q] = 0.f;
    for (int n=0;n<NC;++n){
        size_t base = ((size_t)((b*NC + n)*N_HEADS + h))*4096;
        for (int q=0;q<16;++q){
            int f = tid + q*256;
            int e = f>>6, d = f&63;
            stT[base + d*64 + e] = (bf16_t)st[q];
            st[q] = st[q]*wC + U[base + f];
        }
    }
    size_t ob = ((size_t)(b*N_HEADS + h))*4096;
    for (int q=0;q<16;++q) outState[ob + tid + q*256] = st[q];
}

// ---------------------------------------------------------------------------
// K6: fused per (b,chunk,h): S=(r k^T)*mask -> P=S v (slice-staged) ->
// bias=(r state)*w^i -> LN over d_head (in-register shuffle) -> att bf16.
// ---------------------------------------------------------------------------
__global__ __launch_bounds__(256) void k_att_fused(
    const bf16_t* __restrict__ rb, const bf16_t* __restrict__ kb, const bf16_t* __restrict__ vb,
    const bf16_t* __restrict__ stT, const float* __restrict__ td, const float* __restrict__ tf,
    const float* __restrict__ gx, const float* __restrict__ bx,
    bf16_t* __restrict__ att)
{
    __shared__ __align__(16) char smem[63488];
    bf16_t* rS  = (bf16_t*)smem;               // [128][72]
    bf16_t* kS  = (bf16_t*)(smem + 18432);     // [128][72]; later Sst [128][40], att_s [128][72]
    bf16_t* vT  = (bf16_t*)(smem + 36864);     // [64][136]
    bf16_t* sS  = (bf16_t*)(smem + 54272);     // [64][72]
    bf16_t* Sst = kS;
    bf16_t* att_s = kS;
    const int bid = blockIdx.x;
    const int h = bid & 31, n = (bid>>5)&15, b = bid>>9;
    const int tid = threadIdx.x;
    const int wave = tid>>6, lane = tid&63, quad = lane>>4, l15 = lane&15;
    const size_t row0 = (size_t)b*SEQ + n*CHUNK;
    const int col0 = h*D_HEAD;
    const float lnw = -__expf(td[h]);
    const float u   =  __expf(tf[h]);
    for (int it=0; it<4; ++it){
        int idx = tid + it*256;
        int row = idx>>3, c8 = (idx&7)*8;
        *(bf16x8*)&rS[row*72 + c8] = *(const bf16x8*)&rb[(row0+row)*D_MODEL + col0 + c8];
        *(bf16x8*)&kS[row*72 + c8] = *(const bf16x8*)&kb[(row0+row)*D_MODEL + col0 + c8];
        bf16x8 vv = *(const bf16x8*)&vb[(row0+row)*D_MODEL + col0 + c8];
        for (int q=0;q<8;++q) vT[(c8+q)*136 + row] = vv[q];
    }
    const bf16_t* stg = stT + (size_t)bid*4096;
    for (int it=0; it<2; ++it){
        int idx = tid + it*256;
        int row = idx>>3, c8 = (idx&7)*8;
        *(bf16x8*)&sS[row*72 + c8] = *(const bf16x8*)&stg[row*64 + c8];
    }
    __syncthreads();
    // --- S = r k^T (full 128x128 in registers)
    f32x4 accS[2][8];
    for (int i=0;i<2;++i) for (int j=0;j<8;++j) accS[i][j] = (f32x4){0.f,0.f,0.f,0.f};
    for (int kk=0; kk<2; ++kk){
        bf16x8 af[2], bfr[8];
        for (int i=0;i<2;++i) af[i] = *(const bf16x8*)&rS[(wave*32+i*16+l15)*72 + kk*32 + quad*8];
        for (int j=0;j<8;++j) bfr[j] = *(const bf16x8*)&kS[(j*16+l15)*72 + kk*32 + quad*8];
        for (int i=0;i<2;++i) for (int j=0;j<8;++j)
            accS[i][j] = __builtin_amdgcn_mfma_f32_16x16x32_bf16(af[i], bfr[j], accS[i][j], 0,0,0);
    }
    __syncthreads();   // kS dead; Sst overlays it
    // --- P = (S*mask) v, staged 32 columns at a time
    f32x4 accP[2][4];
    for (int i=0;i<2;++i) for (int j=0;j<4;++j) accP[i][j] = (f32x4){0.f,0.f,0.f,0.f};
    for (int kk=0; kk<4; ++kk){
        for (int i=0;i<2;++i) for (int jj=0;jj<2;++jj) for (int e=0;e<4;++e){
            int si = wave*32 + i*16 + quad*4 + e;
            int sj = kk*32 + jj*16 + l15;
            float m;
            if (si > sj)       m = __expf(lnw * (float)(si-sj-1));
            else if (si == sj) m = u;
            else               m = 0.f;
            Sst[si*40 + jj*16 + l15] = (bf16_t)(accS[i][kk*2+jj][e] * m);
        }
        __syncthreads();
        bf16x8 af[2], bfr[4];
        for (int i=0;i<2;++i) af[i] = *(const bf16x8*)&Sst[(wave*32+i*16+l15)*40 + quad*8];
        for (int j=0;j<4;++j) bfr[j] = *(const bf16x8*)&vT[(j*16+l15)*136 + kk*32 + quad*8];
        for (int i=0;i<2;++i) for (int j=0;j<4;++j)
            accP[i][j] = __builtin_amdgcn_mfma_f32_16x16x32_bf16(af[i], bfr[j], accP[i][j], 0,0,0);
        __syncthreads();
    }
    // --- bias = r @ state (state staged transposed: sS[d][e])
    f32x4 accB[2][4];
    for (int i=0;i<2;++i) for (int j=0;j<4;++j) accB[i][j] = (f32x4){0.f,0.f,0.f,0.f};
    for (int kk=0; kk<2; ++kk){
        bf16x8 af[2], bfr[4];
        for (int i=0;i<2;++i) af[i] = *(const bf16x8*)&rS[(wave*32+i*16+l15)*72 + kk*32 + quad*8];
        for (int j=0;j<4;++j) bfr[j] = *(const bf16x8*)&sS[(j*16+l15)*72 + kk*32 + quad*8];
        for (int i=0;i<2;++i) for (int j=0;j<4;++j)
            accB[i][j] = __builtin_amdgcn_mfma_f32_16x16x32_bf16(af[i], bfr[j], accB[i][j], 0,0,0);
    }
    // --- combine + in-register LayerNorm over d
    float pre[2][4][4];
    float mu_r[2][4], rs_r[2][4];
    for (int i=0;i<2;++i) for (int e=0;e<4;++e){
        int si = wave*32 + i*16 + quad*4 + e;
        float wsi = __expf(lnw * (float)si);
        float s = 0.f, q2 = 0.f;
        for (int j=0;j<4;++j){
            float v = accP[i][j][e] + accB[i][j][e]*wsi;
            pre[i][j][e] = v;
            s += v; q2 += v*v;
        }
        for (int o=1;o<16;o<<=1){ s += __shfl_xor(s,o,64); q2 += __shfl_xor(q2,o,64); }
        float mu = s*(1.f/64.f);
        float var = q2*(1.f/64.f) - mu*mu;
        mu_r[i][e] = mu; rs_r[i][e] = rsqrtf(var + LN_EPS);
    }
    float gxv[4], bxv[4];
    for (int j=0;j<4;++j){ gxv[j] = gx[col0 + j*16 + l15]; bxv[j] = bx[col0 + j*16 + l15]; }
    for (int i=0;i<2;++i) for (int j=0;j<4;++j) for (int e=0;e<4;++e){
        int si = wave*32 + i*16 + quad*4 + e;
        att_s[si*72 + j*16 + l15] = (bf16_t)((pre[i][j][e]-mu_r[i][e])*rs_r[i][e]*gxv[j] + bxv[j]);
    }
    __syncthreads();
    for (int it=0; it<4; ++it){
        int idx = tid + it*256;
        int row = idx>>3, c8 = (idx&7)*8;
        *(bf16x8*)&att[(row0+row)*D_MODEL + col0 + c8] = *(const bf16x8*)&att_s[row*72 + c8];
    }
}

// ---------------------------------------------------------------------------
// Launch. Workspace (>= 224 MiB), aliasing:
//   [0,32)    rxb bf16   -> U f32 (after rkv GEMM)
//   [32,64)   kxb bf16   -> stT bf16
//   [64,96)   vxb bf16   -> att bf16
//   [96,128)  WT[4] bf16 (Wr,Wk,Wv,Wo transposed; Wo alive to end)
//   [128,160) rb, [160,192) kb, [192,224) vb
// ---------------------------------------------------------------------------
extern "C" void kernel_launch(void* const* d_in, const int* in_sizes, int n_in,
                              void* d_out, int out_size, void* d_ws, size_t ws_size,
                              hipStream_t stream) {
    const float* x   = (const float*)d_in[0];
    const float* tmr = (const float*)d_in[1];
    const float* tmk = (const float*)d_in[2];
    const float* tmv = (const float*)d_in[3];
    const float* Wk  = (const float*)d_in[4];
    const float* Wv  = (const float*)d_in[5];
    const float* Wr  = (const float*)d_in[6];
    const float* Wo  = (const float*)d_in[7];
    const float* td  = (const float*)d_in[8];
    const float* tf  = (const float*)d_in[9];
    const float* g1  = (const float*)d_in[10];
    const float* b1  = (const float*)d_in[11];
    const float* gx  = (const float*)d_in[12];
    const float* bx  = (const float*)d_in[13];

    float* out0 = (float*)d_out;
    float* out1 = out0 + (size_t)NTOK*D_MODEL;
    float* out2 = out1 + (size_t)BZ*D_MODEL;

    const size_t MB = 1ull<<20;
    char* ws = (char*)d_ws;
    bf16_t* rxb = (bf16_t*)(ws);
    bf16_t* kxb = (bf16_t*)(ws + 32*MB);
    bf16_t* vxb = (bf16_t*)(ws + 64*MB);
    bf16_t* WTb = (bf16_t*)(ws + 96*MB);          // 4 x 8MB: Wr,Wk,Wv,Wo
    bf16_t* WoT = (bf16_t*)(ws + 120*MB);
    bf16_t* rb  = (bf16_t*)(ws + 128*MB);
    float*  U   = (float*)(ws);                   // after rxb dead
    bf16_t* stT = (bf16_t*)(ws + 32*MB);          // after kxb dead
    bf16_t* att = (bf16_t*)(ws + 64*MB);          // after vxb dead
    bf16_t* kb  = (bf16_t*)(ws + 160*MB);
    bf16_t* vb  = (bf16_t*)(ws + 192*MB);

    k_ln_mix<<<NTOK, 256, 0, stream>>>(x, tmr, tmk, tmv, g1, b1, rxb, kxb, vxb, out1);

    dim3 gT(32, 32, 4);
    k_wt4<<<gT, 256, 0, stream>>>(Wr, Wk, Wv, Wo, WTb);

    dim3 gG3(D_MODEL/128, NTOK/128, 3);   // (16, 64, 3)
    k_gemm_rkv<<<gG3, 256, 0, stream>>>(rxb, WTb, rb);

    const int nblk = BZ*NC*N_HEADS;   // 2048
    k_chunk_U <<<nblk, 256, 0, stream>>>(kb, vb, td, U);
    k_scan    <<<BZ*N_HEADS, 256, 0, stream>>>(U, td, stT, out2);
    k_att_fused<<<nblk, 256, 0, stream>>>(rb, kb, vb, stT, td, tf, gx, bx, att);

    dim3 gG(D_MODEL/128, NTOK/128);
    k_gemm_out<<<gG, 256, 0, stream>>>(att, WoT, out0, x);
}